// Round 1
// baseline (4253.946 us; speedup 1.0000x reference)
//
#include <hip/hip_runtime.h>
#include <hip/hip_bf16.h>

typedef __bf16 bf16_t;
typedef __bf16 bf16x8 __attribute__((ext_vector_type(8)));
typedef __bf16 bf16x4 __attribute__((ext_vector_type(4)));
typedef float  f32x4  __attribute__((ext_vector_type(4)));

#define HID 512
#define BATCH 256
#define TIN 168
#define TOUT 48
#define FEAT 128

__device__ __forceinline__ float sigmoidf_(float x) {
    x = fminf(fmaxf(x, -30.f), 30.f);
    return 1.f / (1.f + __expf(-x));
}
__device__ __forceinline__ float tanhf_(float x) {
    x = fminf(fmaxf(x, -15.f), 15.f);
    float e = __expf(2.f * x);
    return (e - 1.f) / (e + 1.f);
}

// ---------------------------------------------------------------------------
// Cast x (B,T,F) fp32 -> Xbf (T,B,F) bf16
__global__ __launch_bounds__(256)
void cast_x_kernel(const float* __restrict__ x, bf16_t* __restrict__ Xbf) {
    int q = blockIdx.x * 256 + threadIdx.x;          // quad index
    if (q >= BATCH * TIN * (FEAT / 4)) return;
    int f4  = q & 31;
    int rem = q >> 5;
    int t = rem % TIN;
    int b = rem / TIN;
    float4 v = *(const float4*)&x[((size_t)b * TIN + t) * FEAT + f4 * 4];
    bf16x4 o = { (bf16_t)v.x, (bf16_t)v.y, (bf16_t)v.z, (bf16_t)v.w };
    *(bf16x4*)&Xbf[((size_t)t * BATCH + b) * FEAT + f4 * 4] = o;
}

// Build Wcat (2048 x 640) bf16 = [Wih | Whh]
__global__ __launch_bounds__(256)
void cast_wcat_kernel(const float* __restrict__ Wih, const float* __restrict__ Whh,
                      bf16_t* __restrict__ Wcat) {
    int q = blockIdx.x * 256 + threadIdx.x;          // quad index, 2048*160
    int k4 = q % 160;
    int r  = q / 160;
    if (r >= 2048) return;
    int k = k4 * 4;
    float4 v;
    if (k < FEAT) v = *(const float4*)&Wih[(size_t)r * FEAT + k];
    else          v = *(const float4*)&Whh[(size_t)r * HID + (k - FEAT)];
    bf16x4 o = { (bf16_t)v.x, (bf16_t)v.y, (bf16_t)v.z, (bf16_t)v.w };
    *(bf16x4*)&Wcat[(size_t)r * 640 + k] = o;
}

// Cast W_lin (128 x 512) fp32 -> bf16
__global__ __launch_bounds__(256)
void cast_wlin_kernel(const float* __restrict__ W, bf16_t* __restrict__ Wb) {
    int q = blockIdx.x * 256 + threadIdx.x;          // 16384 quads
    if (q >= FEAT * HID / 4) return;
    float4 v = *(const float4*)&W[q * 4];
    bf16x4 o = { (bf16_t)v.x, (bf16_t)v.y, (bf16_t)v.z, (bf16_t)v.w };
    *(bf16x4*)&Wb[q * 4] = o;
}

// Wcomb (2048 x 512) = dec_Wih (2048x128) @ W_lin (128x512) + dec_Whh, bf16 out
__global__ __launch_bounds__(256)
void build_wcomb_kernel(const float* __restrict__ dWih, const float* __restrict__ dWhh,
                        const float* __restrict__ Wlin, bf16_t* __restrict__ Wcomb) {
    __shared__ float As[64][128];
    __shared__ float Bs[128][64];
    int r0 = blockIdx.x * 64, c0 = blockIdx.y * 64;
    int tid = threadIdx.x;
    for (int i = tid; i < 64 * 32; i += 256) {       // 2048 float4 of A
        int rr = i >> 5, cc = (i & 31) << 2;
        *(float4*)&As[rr][cc] = *(const float4*)&dWih[(size_t)(r0 + rr) * 128 + cc];
    }
    for (int i = tid; i < 128 * 16; i += 256) {      // 2048 float4 of B
        int kk = i >> 4, cc = (i & 15) << 2;
        *(float4*)&Bs[kk][cc] = *(const float4*)&Wlin[(size_t)kk * HID + c0 + cc];
    }
    __syncthreads();
    int tx = tid & 15, ty = tid >> 4;
    float acc[4][4] = {};
    for (int k = 0; k < 128; ++k) {
        float a[4], b[4];
        #pragma unroll
        for (int i = 0; i < 4; ++i) a[i] = As[ty * 4 + i][k];
        #pragma unroll
        for (int j = 0; j < 4; ++j) b[j] = Bs[k][tx * 4 + j];
        #pragma unroll
        for (int i = 0; i < 4; ++i)
            #pragma unroll
            for (int j = 0; j < 4; ++j) acc[i][j] += a[i] * b[j];
    }
    for (int i = 0; i < 4; ++i) {
        int r = r0 + ty * 4 + i;
        for (int j = 0; j < 4; ++j) {
            int cc = c0 + tx * 4 + j;
            Wcomb[(size_t)r * HID + cc] = (bf16_t)(acc[i][j] + dWhh[(size_t)r * HID + cc]);
        }
    }
}

// ---------------------------------------------------------------------------
// One LSTM step, fused GEMM + cell update.
// gates(256 x 2048) = [x_t | h] (256 x (S1+512)) @ W^T,  W row-major [2048][K]
// Grid (8,16), block 128 (2 waves). WG tile: 32 batch x 32 hidden (=128 gate cols).
// Wave w handles batch rows [bt*32 + w*16, +16).
// Col-tile n (0..7): gate g=n>>1, hidden half n&1 -> W row (n>>1)*512 + jbase + (n&1)*16 + (lane&15)
// MFMA 16x16x32 bf16; D layout: col = lane&15, row = (lane>>4)*4 + reg.
template <int S1>
__global__ __launch_bounds__(128)
void lstm_step_kernel(const bf16_t* __restrict__ xseg,  // [256][S1] (t-slice), or unused
                      const bf16_t* __restrict__ hin,   // [256][512]
                      const bf16_t* __restrict__ W,     // [2048][S1+512]
                      const float*  __restrict__ bias,  // [2048]
                      float*        __restrict__ c,     // [256][512] fp32, in/out
                      bf16_t*       __restrict__ hout)  // [256][512]
{
    constexpr int K = S1 + HID;
    int tid  = threadIdx.x;
    int wv   = tid >> 6;
    int lane = tid & 63;
    int l15 = lane & 15, l4 = lane >> 4;
    int brow0 = blockIdx.x * 32 + wv * 16;
    int jbase = blockIdx.y * 32;

    int arow = brow0 + l15;
    const bf16_t* hrow = hin + (size_t)arow * HID;
    const bf16_t* xrow = xseg + (size_t)arow * (S1 ? S1 : 1);

    f32x4 acc[8];
    const bf16_t* wrow[8];
    #pragma unroll
    for (int n = 0; n < 8; ++n) {
        int row = (n >> 1) * HID + jbase + (n & 1) * 16 + l15;
        float bv = bias[row];
        acc[n] = (f32x4){bv, bv, bv, bv};
        wrow[n] = W + (size_t)row * K;
    }

    #pragma unroll 4
    for (int kc = 0; kc < K; kc += 32) {
        int ks = kc + l4 * 8;
        bf16x8 af;
        if (S1 && kc < S1) af = *(const bf16x8*)(xrow + ks);
        else               af = *(const bf16x8*)(hrow + (ks - S1));
        #pragma unroll
        for (int n = 0; n < 8; ++n) {
            bf16x8 bfr = *(const bf16x8*)(wrow[n] + ks);
            acc[n] = __builtin_amdgcn_mfma_f32_16x16x32_bf16(af, bfr, acc[n], 0, 0, 0);
        }
    }

    // cell update: lane holds col j = jbase + h16*16 + l15, rows b = brow0 + l4*4 + r
    #pragma unroll
    for (int h16 = 0; h16 < 2; ++h16) {
        int j = jbase + h16 * 16 + l15;
        #pragma unroll
        for (int r = 0; r < 4; ++r) {
            int b = brow0 + l4 * 4 + r;
            float gi = acc[0 + h16][r];
            float gf = acc[2 + h16][r];
            float gg = acc[4 + h16][r];
            float go = acc[6 + h16][r];
            size_t idx = (size_t)b * HID + j;
            float cv = c[idx];
            float cn = sigmoidf_(gf) * cv + sigmoidf_(gi) * tanhf_(gg);
            float hv = sigmoidf_(go) * tanhf_(cn);
            c[idx] = cn;
            hout[idx] = (bf16_t)hv;
        }
    }
}

// ---------------------------------------------------------------------------
// Final projection: out[b,t,f] = sum_j Hdec[t][b][j] * Wlin[f][j]
// rows (t*256+b) = 12288, cols 128, K=512. Block 128 (2 waves), 32 rows/WG.
__global__ __launch_bounds__(128)
void final_proj_kernel(const bf16_t* __restrict__ Hdec, const bf16_t* __restrict__ Wlin,
                       float* __restrict__ out) {
    int tid = threadIdx.x;
    int wv = tid >> 6, lane = tid & 63;
    int l15 = lane & 15, l4 = lane >> 4;
    int row0 = blockIdx.x * 32 + wv * 16;
    const bf16_t* arow = Hdec + (size_t)(row0 + l15) * HID;
    f32x4 acc[8];
    #pragma unroll
    for (int n = 0; n < 8; ++n) acc[n] = (f32x4){0.f, 0.f, 0.f, 0.f};
    #pragma unroll 4
    for (int kc = 0; kc < HID; kc += 32) {
        bf16x8 af = *(const bf16x8*)(arow + kc + l4 * 8);
        #pragma unroll
        for (int n = 0; n < 8; ++n) {
            bf16x8 bfr = *(const bf16x8*)(Wlin + (size_t)(n * 16 + l15) * HID + kc + l4 * 8);
            acc[n] = __builtin_amdgcn_mfma_f32_16x16x32_bf16(af, bfr, acc[n], 0, 0, 0);
        }
    }
    #pragma unroll
    for (int n = 0; n < 8; ++n) {
        int f = n * 16 + l15;
        #pragma unroll
        for (int r = 0; r < 4; ++r) {
            int row = row0 + l4 * 4 + r;
            int t = row >> 8;
            int b = row & 255;
            out[(size_t)b * (TOUT * FEAT) + (size_t)t * FEAT + f] = acc[n][r];
        }
    }
}

// ---------------------------------------------------------------------------
extern "C" void kernel_launch(void* const* d_in, const int* in_sizes, int n_in,
                              void* d_out, int out_size, void* d_ws, size_t ws_size,
                              hipStream_t stream) {
    const float* x       = (const float*)d_in[0];
    const float* enc_Wih = (const float*)d_in[1];
    const float* enc_Whh = (const float*)d_in[2];
    const float* enc_b   = (const float*)d_in[3];
    const float* dec_Wih = (const float*)d_in[4];
    const float* dec_Whh = (const float*)d_in[5];
    const float* dec_b   = (const float*)d_in[6];
    const float* W_lin   = (const float*)d_in[7];
    float* out = (float*)d_out;

    // workspace layout (256B aligned)
    char* p = (char*)d_ws;
    auto alloc = [&](size_t bytes) -> void* {
        void* r = (void*)p;
        p += (bytes + 255) & ~(size_t)255;
        return r;
    };
    bf16_t* Xbf    = (bf16_t*)alloc((size_t)TIN * BATCH * FEAT * 2);   // 11 MB
    bf16_t* Wenc   = (bf16_t*)alloc((size_t)2048 * 640 * 2);           // 2.5 MB
    bf16_t* Wdec1  = (bf16_t*)alloc((size_t)2048 * 640 * 2);           // 2.5 MB
    bf16_t* Wcomb  = (bf16_t*)alloc((size_t)2048 * HID * 2);           // 2 MB
    bf16_t* Wlinb  = (bf16_t*)alloc((size_t)FEAT * HID * 2);           // 128 KB
    float*  cbuf   = (float*)alloc((size_t)BATCH * HID * 4);           // 512 KB
    bf16_t* hbuf0  = (bf16_t*)alloc((size_t)BATCH * HID * 2);          // 256 KB
    bf16_t* hbuf1  = (bf16_t*)alloc((size_t)BATCH * HID * 2);          // 256 KB
    bf16_t* Hdec   = (bf16_t*)alloc((size_t)TOUT * BATCH * HID * 2);   // 12.5 MB

    // init state
    hipMemsetAsync(cbuf, 0, (size_t)BATCH * HID * 4, stream);
    hipMemsetAsync(hbuf0, 0, (size_t)BATCH * HID * 2, stream);

    // precompute
    cast_x_kernel<<<(BATCH * TIN * (FEAT / 4) + 255) / 256, 256, 0, stream>>>(x, Xbf);
    cast_wcat_kernel<<<(2048 * 160 + 255) / 256, 256, 0, stream>>>(enc_Wih, enc_Whh, Wenc);
    cast_wcat_kernel<<<(2048 * 160 + 255) / 256, 256, 0, stream>>>(dec_Wih, dec_Whh, Wdec1);
    cast_wlin_kernel<<<(FEAT * HID / 4 + 255) / 256, 256, 0, stream>>>(W_lin, Wlinb);
    build_wcomb_kernel<<<dim3(2048 / 64, HID / 64), 256, 0, stream>>>(dec_Wih, dec_Whh, W_lin, Wcomb);

    dim3 sgrid(8, 16);
    // encoder: 168 steps, ping-pong h
    bf16_t* hb[2] = {hbuf0, hbuf1};
    for (int t = 0; t < TIN; ++t) {
        lstm_step_kernel<FEAT><<<sgrid, 128, 0, stream>>>(
            Xbf + (size_t)t * BATCH * FEAT, hb[t & 1], Wenc, enc_b, cbuf, hb[(t + 1) & 1]);
    }
    // decoder step 0: input = x[:, -1, :], full dec weights
    lstm_step_kernel<FEAT><<<sgrid, 128, 0, stream>>>(
        Xbf + (size_t)(TIN - 1) * BATCH * FEAT, hb[TIN & 1], Wdec1, dec_b, cbuf, Hdec);
    // decoder steps 1..47: folded weights (K=512)
    for (int t = 1; t < TOUT; ++t) {
        lstm_step_kernel<0><<<sgrid, 128, 0, stream>>>(
            Xbf /*unused*/, Hdec + (size_t)(t - 1) * BATCH * HID, Wcomb, dec_b, cbuf,
            Hdec + (size_t)t * BATCH * HID);
    }
    // final projection for all 48 outputs
    final_proj_kernel<<<(TOUT * BATCH) / 32, 128, 0, stream>>>(Hdec, Wlinb, out);
}

// Round 3
// 2962.497 us; speedup vs baseline: 1.4359x; 1.4359x over previous
//
#include <hip/hip_runtime.h>
#include <hip/hip_bf16.h>

typedef __bf16 bf16_t;
typedef __bf16 bf16x8 __attribute__((ext_vector_type(8)));
typedef __bf16 bf16x4 __attribute__((ext_vector_type(4)));
typedef float  f32x4  __attribute__((ext_vector_type(4)));

#define HID 512
#define BATCH 256
#define TIN 168
#define TOUT 48
#define FEAT 128
#define NSTEPS (TIN + TOUT)   // 216
#define NGRP 8                // batch groups (one per XCD under round-robin)
#define NJT 32                // blocks per group (j-tiles of 16)
#define GRPB 32               // batch rows per group

__device__ __forceinline__ float sigmoidf_(float x) {
    x = fminf(fmaxf(x, -30.f), 30.f);
    return 1.f / (1.f + __expf(-x));
}
__device__ __forceinline__ float tanhf_(float x) {
    x = fminf(fmaxf(x, -15.f), 15.f);
    float e = __expf(2.f * x);
    return (e - 1.f) / (e + 1.f);
}

// ---------------------------------------------------------------------------
// Cast x (B,T,F) fp32 -> Xbf (T,B,F) bf16
__global__ __launch_bounds__(256)
void cast_x_kernel(const float* __restrict__ x, bf16_t* __restrict__ Xbf) {
    int q = blockIdx.x * 256 + threadIdx.x;
    if (q >= BATCH * TIN * (FEAT / 4)) return;
    int f4  = q & 31;
    int rem = q >> 5;
    int t = rem % TIN;
    int b = rem / TIN;
    float4 v = *(const float4*)&x[((size_t)b * TIN + t) * FEAT + f4 * 4];
    bf16x4 o = { (bf16_t)v.x, (bf16_t)v.y, (bf16_t)v.z, (bf16_t)v.w };
    *(bf16x4*)&Xbf[((size_t)t * BATCH + b) * FEAT + f4 * 4] = o;
}

// Build Wcat (2048 x 640) bf16 = [Wih | Whh]
__global__ __launch_bounds__(256)
void cast_wcat_kernel(const float* __restrict__ Wih, const float* __restrict__ Whh,
                      bf16_t* __restrict__ Wcat) {
    int q = blockIdx.x * 256 + threadIdx.x;
    int k4 = q % 160;
    int r  = q / 160;
    if (r >= 2048) return;
    int k = k4 * 4;
    float4 v;
    if (k < FEAT) v = *(const float4*)&Wih[(size_t)r * FEAT + k];
    else          v = *(const float4*)&Whh[(size_t)r * HID + (k - FEAT)];
    bf16x4 o = { (bf16_t)v.x, (bf16_t)v.y, (bf16_t)v.z, (bf16_t)v.w };
    *(bf16x4*)&Wcat[(size_t)r * 640 + k] = o;
}

// Cast W_lin (128 x 512) fp32 -> bf16
__global__ __launch_bounds__(256)
void cast_wlin_kernel(const float* __restrict__ W, bf16_t* __restrict__ Wb) {
    int q = blockIdx.x * 256 + threadIdx.x;
    if (q >= FEAT * HID / 4) return;
    float4 v = *(const float4*)&W[q * 4];
    bf16x4 o = { (bf16_t)v.x, (bf16_t)v.y, (bf16_t)v.z, (bf16_t)v.w };
    *(bf16x4*)&Wb[q * 4] = o;
}

// Wcomb (2048 x 512) = dec_Wih (2048x128) @ W_lin (128x512) + dec_Whh, bf16 out
__global__ __launch_bounds__(256)
void build_wcomb_kernel(const float* __restrict__ dWih, const float* __restrict__ dWhh,
                        const float* __restrict__ Wlin, bf16_t* __restrict__ Wcomb) {
    __shared__ float As[64][128];
    __shared__ float Bs[128][64];
    int r0 = blockIdx.x * 64, c0 = blockIdx.y * 64;
    int tid = threadIdx.x;
    for (int i = tid; i < 64 * 32; i += 256) {
        int rr = i >> 5, cc = (i & 31) << 2;
        *(float4*)&As[rr][cc] = *(const float4*)&dWih[(size_t)(r0 + rr) * 128 + cc];
    }
    for (int i = tid; i < 128 * 16; i += 256) {
        int kk = i >> 4, cc = (i & 15) << 2;
        *(float4*)&Bs[kk][cc] = *(const float4*)&Wlin[(size_t)kk * HID + c0 + cc];
    }
    __syncthreads();
    int tx = tid & 15, ty = tid >> 4;
    float acc[4][4] = {};
    for (int k = 0; k < 128; ++k) {
        float a[4], b[4];
        #pragma unroll
        for (int i = 0; i < 4; ++i) a[i] = As[ty * 4 + i][k];
        #pragma unroll
        for (int j = 0; j < 4; ++j) b[j] = Bs[k][tx * 4 + j];
        #pragma unroll
        for (int i = 0; i < 4; ++i)
            #pragma unroll
            for (int j = 0; j < 4; ++j) acc[i][j] += a[i] * b[j];
    }
    for (int i = 0; i < 4; ++i) {
        int r = r0 + ty * 4 + i;
        for (int j = 0; j < 4; ++j) {
            int cc = c0 + tx * 4 + j;
            Wcomb[(size_t)r * HID + cc] = (bf16_t)(acc[i][j] + dWhh[(size_t)r * HID + cc]);
        }
    }
}

// ---------------------------------------------------------------------------
// Persistent seq2seq LSTM kernel.
// 256 blocks x 256 threads. Block -> (group g = bid&7, j-tile jt = bid>>3).
// Group g owns batch rows [g*32, g*32+32); block owns hidden cols [jt*16,+16).
// 4 waves/block: wave = (gp<<1)|bh; bh = batch half (16 rows), gp = K half.
// Each wave: 4 gates x 16 cols x K/2 weights in 40 bf16x8 register fragments.
// Per step: MFMA partial gates, LDS-exchange K-halves, gp=0 waves update c
// (register-resident) and store h (bf16). Group-wide step barrier via
// agent-scope atomic counter per (step, group).

__device__ __forceinline__ void cell_finish(
    f32x4 (&acc)[4], float (&cacc)[4], float (*Ex)[GRPB][17],
    int gp, int bh, int l4, int l15, int b0, int jcol,
    bf16_t* __restrict__ hnext)
{
    if (gp == 1) {
        #pragma unroll
        for (int q = 0; q < 4; ++q)
            #pragma unroll
            for (int r = 0; r < 4; ++r)
                Ex[q][bh * 16 + l4 * 4 + r][l15] = acc[q][r];
    }
    __syncthreads();
    if (gp == 0) {
        #pragma unroll
        for (int q = 0; q < 4; ++q)
            #pragma unroll
            for (int r = 0; r < 4; ++r)
                acc[q][r] += Ex[q][bh * 16 + l4 * 4 + r][l15];
        #pragma unroll
        for (int r = 0; r < 4; ++r) {
            float cn = sigmoidf_(acc[1][r]) * cacc[r] + sigmoidf_(acc[0][r]) * tanhf_(acc[2][r]);
            cacc[r] = cn;
            float hv = sigmoidf_(acc[3][r]) * tanhf_(cn);
            int row = b0 + l4 * 4 + r;
            hnext[(size_t)row * HID + jcol] = (bf16_t)hv;
        }
        asm volatile("s_waitcnt vmcnt(0)" ::: "memory");
    }
    __syncthreads();
}

__device__ __forceinline__ void group_wait(unsigned int* cnt, int t, int g, int tid) {
    if (tid == 0) {
        while (__hip_atomic_load(&cnt[t * NGRP + g], __ATOMIC_RELAXED,
                                 __HIP_MEMORY_SCOPE_AGENT) < (unsigned)NJT)
            __builtin_amdgcn_s_sleep(1);
    }
    __syncthreads();
    __builtin_amdgcn_fence(__ATOMIC_ACQUIRE, "agent");
}

__device__ __forceinline__ void group_arrive(unsigned int* cnt, int t, int g, int tid) {
    if (tid == 0)
        __hip_atomic_fetch_add(&cnt[t * NGRP + g], 1u, __ATOMIC_RELEASE,
                               __HIP_MEMORY_SCOPE_AGENT);
}

__global__ __launch_bounds__(256, 1)
void lstm_persist(const bf16_t* __restrict__ Xbf,
                  const bf16_t* __restrict__ Wenc, const float* __restrict__ enc_b,
                  const bf16_t* __restrict__ Wdec1, const bf16_t* __restrict__ Wcomb,
                  const float* __restrict__ dec_b,
                  bf16_t* __restrict__ hbufA, bf16_t* __restrict__ hbufB,
                  bf16_t* __restrict__ Hdec, unsigned int* __restrict__ cnt)
{
    __shared__ float Ex[4][GRPB][17];
    const int bid = blockIdx.x;
    const int g   = bid & (NGRP - 1);
    const int jt  = bid >> 3;
    const int j0  = jt * 16;
    const int tid = threadIdx.x;
    const int wave = tid >> 6, lane = tid & 63;
    const int l15 = lane & 15, l4 = lane >> 4;
    const int bh = wave & 1, gp = wave >> 1;
    const int b0 = g * GRPB + bh * 16;
    const int arow = b0 + l15;   // A-operand (batch) row this lane loads
    const int jcol = j0 + l15;   // output hidden column

    float biasE[4], biasD[4];
    #pragma unroll
    for (int q = 0; q < 4; ++q) {
        biasE[q] = enc_b[q * HID + jcol];
        biasD[q] = dec_b[q * HID + jcol];
    }
    float cacc[4] = {0.f, 0.f, 0.f, 0.f};

    bf16x8 Breg[40];
    const int kc0 = gp * 320;    // K-half base for K=640 phases

    // ---- encoder weight fragments (K=640)
    #pragma unroll
    for (int q = 0; q < 4; ++q)
        #pragma unroll
        for (int i = 0; i < 10; ++i)
            Breg[q * 10 + i] = *(const bf16x8*)(
                Wenc + (size_t)(q * HID + jcol) * 640 + kc0 + i * 32 + l4 * 8);

    // ================= encoder: t = 0..167 =================
    for (int t = 0; t < TIN; ++t) {
        if (t > 0) group_wait(cnt, t - 1, g, tid);
        const bf16_t* hb = (t & 1) ? hbufB : hbufA;
        bf16_t* hn       = (t & 1) ? hbufA : hbufB;
        f32x4 acc[4];
        #pragma unroll
        for (int q = 0; q < 4; ++q) {
            float bv = (gp == 0) ? biasE[q] : 0.f;
            acc[q] = (f32x4){bv, bv, bv, bv};
        }
        const bf16_t* xb  = Xbf + ((size_t)t * BATCH + arow) * FEAT + l4 * 8;
        const bf16_t* hbp = hb + (size_t)arow * HID + l4 * 8;
        #pragma unroll
        for (int i = 0; i < 10; ++i) {
            int kc = kc0 + i * 32;
            const bf16_t* ap = (kc < FEAT) ? (xb + kc) : (hbp + (kc - FEAT));
            bf16x8 a = *(const bf16x8*)ap;
            #pragma unroll
            for (int q = 0; q < 4; ++q)
                acc[q] = __builtin_amdgcn_mfma_f32_16x16x32_bf16(a, Breg[q * 10 + i], acc[q], 0, 0, 0);
        }
        cell_finish(acc, cacc, Ex, gp, bh, l4, l15, b0, jcol, hn);
        group_arrive(cnt, t, g, tid);
    }

    // ---- decoder step 0 weights (Wdec1, K=640) -- load before waiting
    #pragma unroll
    for (int q = 0; q < 4; ++q)
        #pragma unroll
        for (int i = 0; i < 10; ++i)
            Breg[q * 10 + i] = *(const bf16x8*)(
                Wdec1 + (size_t)(q * HID + jcol) * 640 + kc0 + i * 32 + l4 * 8);

    // ================= decoder step 0: t = 168 =================
    {
        const int t = TIN;
        group_wait(cnt, t - 1, g, tid);
        // h_168 lives in hbufA (written at t=167)
        f32x4 acc[4];
        #pragma unroll
        for (int q = 0; q < 4; ++q) {
            float bv = (gp == 0) ? biasD[q] : 0.f;
            acc[q] = (f32x4){bv, bv, bv, bv};
        }
        const bf16_t* xb  = Xbf + ((size_t)(TIN - 1) * BATCH + arow) * FEAT + l4 * 8;
        const bf16_t* hbp = hbufA + (size_t)arow * HID + l4 * 8;
        #pragma unroll
        for (int i = 0; i < 10; ++i) {
            int kc = kc0 + i * 32;
            const bf16_t* ap = (kc < FEAT) ? (xb + kc) : (hbp + (kc - FEAT));
            bf16x8 a = *(const bf16x8*)ap;
            #pragma unroll
            for (int q = 0; q < 4; ++q)
                acc[q] = __builtin_amdgcn_mfma_f32_16x16x32_bf16(a, Breg[q * 10 + i], acc[q], 0, 0, 0);
        }
        cell_finish(acc, cacc, Ex, gp, bh, l4, l15, b0, jcol, Hdec);
        group_arrive(cnt, t, g, tid);
    }

    // ---- folded decoder weights (Wcomb, K=512)
    const int kd0 = gp * 256;
    #pragma unroll
    for (int q = 0; q < 4; ++q)
        #pragma unroll
        for (int i = 0; i < 8; ++i)
            Breg[q * 8 + i] = *(const bf16x8*)(
                Wcomb + (size_t)(q * HID + jcol) * HID + kd0 + i * 32 + l4 * 8);

    // ================= decoder: t = 169..215 =================
    for (int t = TIN + 1; t < NSTEPS; ++t) {
        group_wait(cnt, t - 1, g, tid);
        const bf16_t* hprev = Hdec + (size_t)(t - 1 - TIN) * BATCH * HID
                                   + (size_t)arow * HID + l4 * 8;
        f32x4 acc[4];
        #pragma unroll
        for (int q = 0; q < 4; ++q) {
            float bv = (gp == 0) ? biasD[q] : 0.f;
            acc[q] = (f32x4){bv, bv, bv, bv};
        }
        #pragma unroll
        for (int i = 0; i < 8; ++i) {
            bf16x8 a = *(const bf16x8*)(hprev + kd0 + i * 32);
            #pragma unroll
            for (int q = 0; q < 4; ++q)
                acc[q] = __builtin_amdgcn_mfma_f32_16x16x32_bf16(a, Breg[q * 8 + i], acc[q], 0, 0, 0);
        }
        cell_finish(acc, cacc, Ex, gp, bh, l4, l15, b0, jcol,
                    Hdec + (size_t)(t - TIN) * BATCH * HID);
        group_arrive(cnt, t, g, tid);
    }
}

// ---------------------------------------------------------------------------
// Final projection: out[b,t,f] = sum_j Hdec[t][b][j] * Wlin[f][j]
__global__ __launch_bounds__(128)
void final_proj_kernel(const bf16_t* __restrict__ Hdec, const bf16_t* __restrict__ Wlin,
                       float* __restrict__ out) {
    int tid = threadIdx.x;
    int wv = tid >> 6, lane = tid & 63;
    int l15 = lane & 15, l4 = lane >> 4;
    int row0 = blockIdx.x * 32 + wv * 16;
    const bf16_t* arow = Hdec + (size_t)(row0 + l15) * HID;
    f32x4 acc[8];
    #pragma unroll
    for (int n = 0; n < 8; ++n) acc[n] = (f32x4){0.f, 0.f, 0.f, 0.f};
    #pragma unroll 4
    for (int kc = 0; kc < HID; kc += 32) {
        bf16x8 af = *(const bf16x8*)(arow + kc + l4 * 8);
        #pragma unroll
        for (int n = 0; n < 8; ++n) {
            bf16x8 bfr = *(const bf16x8*)(Wlin + (size_t)(n * 16 + l15) * HID + kc + l4 * 8);
            acc[n] = __builtin_amdgcn_mfma_f32_16x16x32_bf16(af, bfr, acc[n], 0, 0, 0);
        }
    }
    #pragma unroll
    for (int n = 0; n < 8; ++n) {
        int f = n * 16 + l15;
        #pragma unroll
        for (int r = 0; r < 4; ++r) {
            int row = row0 + l4 * 4 + r;
            int t = row >> 8;
            int b = row & 255;
            out[(size_t)b * (TOUT * FEAT) + (size_t)t * FEAT + f] = acc[n][r];
        }
    }
}

// ---------------------------------------------------------------------------
extern "C" void kernel_launch(void* const* d_in, const int* in_sizes, int n_in,
                              void* d_out, int out_size, void* d_ws, size_t ws_size,
                              hipStream_t stream) {
    const float* x       = (const float*)d_in[0];
    const float* enc_Wih = (const float*)d_in[1];
    const float* enc_Whh = (const float*)d_in[2];
    const float* enc_b   = (const float*)d_in[3];
    const float* dec_Wih = (const float*)d_in[4];
    const float* dec_Whh = (const float*)d_in[5];
    const float* dec_b   = (const float*)d_in[6];
    const float* W_lin   = (const float*)d_in[7];
    float* out = (float*)d_out;

    char* p = (char*)d_ws;
    auto alloc = [&](size_t bytes) -> void* {
        void* r = (void*)p;
        p += (bytes + 255) & ~(size_t)255;
        return r;
    };
    bf16_t* Xbf    = (bf16_t*)alloc((size_t)TIN * BATCH * FEAT * 2);   // 11 MB
    bf16_t* Wenc   = (bf16_t*)alloc((size_t)2048 * 640 * 2);           // 2.6 MB
    bf16_t* Wdec1  = (bf16_t*)alloc((size_t)2048 * 640 * 2);           // 2.6 MB
    bf16_t* Wcomb  = (bf16_t*)alloc((size_t)2048 * HID * 2);           // 2.1 MB
    bf16_t* Wlinb  = (bf16_t*)alloc((size_t)FEAT * HID * 2);           // 128 KB
    bf16_t* hbufA  = (bf16_t*)alloc((size_t)BATCH * HID * 2);          // 256 KB
    bf16_t* hbufB  = (bf16_t*)alloc((size_t)BATCH * HID * 2);          // 256 KB
    bf16_t* Hdec   = (bf16_t*)alloc((size_t)TOUT * BATCH * HID * 2);   // 12.6 MB
    unsigned int* cnt = (unsigned int*)alloc((size_t)NSTEPS * NGRP * 4);

    // per-launch state init (replay-safe)
    (void)hipMemsetAsync(hbufA, 0, (size_t)BATCH * HID * 2, stream);
    (void)hipMemsetAsync(cnt, 0, (size_t)NSTEPS * NGRP * 4, stream);

    // precompute
    cast_x_kernel<<<(BATCH * TIN * (FEAT / 4) + 255) / 256, 256, 0, stream>>>(x, Xbf);
    cast_wcat_kernel<<<(2048 * 160 + 255) / 256, 256, 0, stream>>>(enc_Wih, enc_Whh, Wenc);
    cast_wcat_kernel<<<(2048 * 160 + 255) / 256, 256, 0, stream>>>(dec_Wih, dec_Whh, Wdec1);
    cast_wlin_kernel<<<(FEAT * HID / 4 + 255) / 256, 256, 0, stream>>>(W_lin, Wlinb);
    build_wcomb_kernel<<<dim3(2048 / 64, HID / 64), 256, 0, stream>>>(dec_Wih, dec_Whh, W_lin, Wcomb);

    // all 216 recurrent steps in one persistent kernel
    lstm_persist<<<NGRP * NJT, 256, 0, stream>>>(Xbf, Wenc, enc_b, Wdec1, Wcomb, dec_b,
                                                 hbufA, hbufB, Hdec, cnt);

    // batched output projection (48 x 256 rows @ W_lin^T)
    final_proj_kernel<<<(TOUT * BATCH) / 32, 128, 0, stream>>>(Hdec, Wlinb, out);
}

// Round 4
// 1053.511 us; speedup vs baseline: 4.0379x; 2.8120x over previous
//
#include <hip/hip_runtime.h>
#include <hip/hip_bf16.h>

typedef __bf16 bf16_t;
typedef __bf16 bf16x8 __attribute__((ext_vector_type(8)));
typedef __bf16 bf16x4 __attribute__((ext_vector_type(4)));
typedef float  f32x4  __attribute__((ext_vector_type(4)));

#define HID 512
#define BATCH 256
#define TIN 168
#define TOUT 48
#define FEAT 128
#define NSTEPS (TIN + TOUT)   // 216
#define NGRP 8                // batch groups
#define NJT 32                // blocks per group (j-tiles of 16)
#define GRPB 32               // batch rows per group

__device__ __forceinline__ float sigmoidf_(float x) {
    x = fminf(fmaxf(x, -30.f), 30.f);
    return 1.f / (1.f + __expf(-x));
}
__device__ __forceinline__ float tanhf_(float x) {
    x = fminf(fmaxf(x, -15.f), 15.f);
    float e = __expf(2.f * x);
    return (e - 1.f) / (e + 1.f);
}

// Coherent (IC-through) 16B bf16 load / 2B store: RELAXED system-scope atomics
// compile to global_load/store ... sc0 sc1 — no wbl2/inv cache maintenance.
__device__ __forceinline__ bf16x8 ld_h8(const bf16_t* p) {
    union { unsigned long long q[2]; bf16x8 v; } u;
    u.q[0] = __hip_atomic_load((const unsigned long long*)p,     __ATOMIC_RELAXED,
                               __HIP_MEMORY_SCOPE_SYSTEM);
    u.q[1] = __hip_atomic_load((const unsigned long long*)p + 1, __ATOMIC_RELAXED,
                               __HIP_MEMORY_SCOPE_SYSTEM);
    return u.v;
}
__device__ __forceinline__ void st_h(bf16_t* p, float v) {
    bf16_t b = (bf16_t)v;
    unsigned short u;
    __builtin_memcpy(&u, &b, 2);
    __hip_atomic_store((unsigned short*)p, u, __ATOMIC_RELAXED, __HIP_MEMORY_SCOPE_SYSTEM);
}

// ---------------------------------------------------------------------------
// Cast x (B,T,F) fp32 -> Xbf (T,B,F) bf16
__global__ __launch_bounds__(256)
void cast_x_kernel(const float* __restrict__ x, bf16_t* __restrict__ Xbf) {
    int q = blockIdx.x * 256 + threadIdx.x;
    if (q >= BATCH * TIN * (FEAT / 4)) return;
    int f4  = q & 31;
    int rem = q >> 5;
    int t = rem % TIN;
    int b = rem / TIN;
    float4 v = *(const float4*)&x[((size_t)b * TIN + t) * FEAT + f4 * 4];
    bf16x4 o = { (bf16_t)v.x, (bf16_t)v.y, (bf16_t)v.z, (bf16_t)v.w };
    *(bf16x4*)&Xbf[((size_t)t * BATCH + b) * FEAT + f4 * 4] = o;
}

// Build Wcat (2048 x 640) bf16 = [Wih | Whh]
__global__ __launch_bounds__(256)
void cast_wcat_kernel(const float* __restrict__ Wih, const float* __restrict__ Whh,
                      bf16_t* __restrict__ Wcat) {
    int q = blockIdx.x * 256 + threadIdx.x;
    int k4 = q % 160;
    int r  = q / 160;
    if (r >= 2048) return;
    int k = k4 * 4;
    float4 v;
    if (k < FEAT) v = *(const float4*)&Wih[(size_t)r * FEAT + k];
    else          v = *(const float4*)&Whh[(size_t)r * HID + (k - FEAT)];
    bf16x4 o = { (bf16_t)v.x, (bf16_t)v.y, (bf16_t)v.z, (bf16_t)v.w };
    *(bf16x4*)&Wcat[(size_t)r * 640 + k] = o;
}

// Cast W_lin (128 x 512) fp32 -> bf16
__global__ __launch_bounds__(256)
void cast_wlin_kernel(const float* __restrict__ W, bf16_t* __restrict__ Wb) {
    int q = blockIdx.x * 256 + threadIdx.x;
    if (q >= FEAT * HID / 4) return;
    float4 v = *(const float4*)&W[q * 4];
    bf16x4 o = { (bf16_t)v.x, (bf16_t)v.y, (bf16_t)v.z, (bf16_t)v.w };
    *(bf16x4*)&Wb[q * 4] = o;
}

// Wcomb (2048 x 512) = dec_Wih (2048x128) @ W_lin (128x512) + dec_Whh, bf16 out
__global__ __launch_bounds__(256)
void build_wcomb_kernel(const float* __restrict__ dWih, const float* __restrict__ dWhh,
                        const float* __restrict__ Wlin, bf16_t* __restrict__ Wcomb) {
    __shared__ float As[64][128];
    __shared__ float Bs[128][64];
    int r0 = blockIdx.x * 64, c0 = blockIdx.y * 64;
    int tid = threadIdx.x;
    for (int i = tid; i < 64 * 32; i += 256) {
        int rr = i >> 5, cc = (i & 31) << 2;
        *(float4*)&As[rr][cc] = *(const float4*)&dWih[(size_t)(r0 + rr) * 128 + cc];
    }
    for (int i = tid; i < 128 * 16; i += 256) {
        int kk = i >> 4, cc = (i & 15) << 2;
        *(float4*)&Bs[kk][cc] = *(const float4*)&Wlin[(size_t)kk * HID + c0 + cc];
    }
    __syncthreads();
    int tx = tid & 15, ty = tid >> 4;
    float acc[4][4] = {};
    for (int k = 0; k < 128; ++k) {
        float a[4], b[4];
        #pragma unroll
        for (int i = 0; i < 4; ++i) a[i] = As[ty * 4 + i][k];
        #pragma unroll
        for (int j = 0; j < 4; ++j) b[j] = Bs[k][tx * 4 + j];
        #pragma unroll
        for (int i = 0; i < 4; ++i)
            #pragma unroll
            for (int j = 0; j < 4; ++j) acc[i][j] += a[i] * b[j];
    }
    for (int i = 0; i < 4; ++i) {
        int r = r0 + ty * 4 + i;
        for (int j = 0; j < 4; ++j) {
            int cc = c0 + tx * 4 + j;
            Wcomb[(size_t)r * HID + cc] = (bf16_t)(acc[i][j] + dWhh[(size_t)r * HID + cc]);
        }
    }
}

// ---------------------------------------------------------------------------
// Persistent seq2seq LSTM. 256 blocks x 256 threads.
// Block -> (group g = bid&7, j-tile jt = bid>>3). Group owns 32 batch rows;
// block owns 16 hidden cols. 4 waves: bh = batch half, gp = K half.
// Weights pinned in VGPRs (asm identity prevents rematerialization).
// h exchanged through IC via sc0sc1 (system-relaxed) loads/stores; sync via
// per-block epoch flags (no RMW, no acquire/release cache maintenance).

__device__ __forceinline__ void cell_finish(
    f32x4 (&acc)[4], float (&cacc)[4], float (*Ex)[GRPB][18],
    int gp, int bh, int l4, int l15, int b0, int jcol,
    bf16_t* __restrict__ hnext)
{
    if (gp == 1) {
        #pragma unroll
        for (int q = 0; q < 4; ++q)
            #pragma unroll
            for (int r = 0; r < 4; ++r)
                Ex[q][bh * 16 + l4 * 4 + r][l15] = acc[q][r];
    }
    __syncthreads();
    if (gp == 0) {
        #pragma unroll
        for (int q = 0; q < 4; ++q)
            #pragma unroll
            for (int r = 0; r < 4; ++r)
                acc[q][r] += Ex[q][bh * 16 + l4 * 4 + r][l15];
        #pragma unroll
        for (int r = 0; r < 4; ++r) {
            float cn = sigmoidf_(acc[1][r]) * cacc[r] + sigmoidf_(acc[0][r]) * tanhf_(acc[2][r]);
            cacc[r] = cn;
            float hv = sigmoidf_(acc[3][r]) * tanhf_(cn);
            int row = b0 + l4 * 4 + r;
            st_h(hnext + (size_t)row * HID + jcol, hv);
        }
        // write-through stores acked at IC before the flag store (after barrier)
        asm volatile("s_waitcnt vmcnt(0)" ::: "memory");
    }
    __syncthreads();
}

// wait until all 32 blocks of group g have flag >= epoch
__device__ __forceinline__ void group_wait(const unsigned int* flags, int g, int tid,
                                           unsigned int epoch) {
    if (tid < NJT) {
        while (__hip_atomic_load(&flags[g * NJT + tid], __ATOMIC_RELAXED,
                                 __HIP_MEMORY_SCOPE_SYSTEM) < epoch)
            __builtin_amdgcn_s_sleep(1);
    }
    __syncthreads();
}

__device__ __forceinline__ void group_arrive(unsigned int* flags, int g, int jt, int tid,
                                             unsigned int epoch) {
    if (tid == 0)
        __hip_atomic_store(&flags[g * NJT + jt], epoch, __ATOMIC_RELAXED,
                           __HIP_MEMORY_SCOPE_SYSTEM);
}

__global__ __launch_bounds__(256, 1)
void lstm_persist(const bf16_t* __restrict__ Xbf,
                  const bf16_t* __restrict__ Wenc, const float* __restrict__ enc_b,
                  const bf16_t* __restrict__ Wdec1, const bf16_t* __restrict__ Wcomb,
                  const float* __restrict__ dec_b,
                  bf16_t* __restrict__ hbufA, bf16_t* __restrict__ hbufB,
                  bf16_t* __restrict__ Hdec, unsigned int* __restrict__ flags)
{
    __shared__ float Ex[4][GRPB][18];
    const int bid = blockIdx.x;
    const int g   = bid & (NGRP - 1);
    const int jt  = bid >> 3;
    const int j0  = jt * 16;
    const int tid = threadIdx.x;
    const int wave = tid >> 6, lane = tid & 63;
    const int l15 = lane & 15, l4 = lane >> 4;
    const int bh = wave & 1, gp = wave >> 1;
    const int b0 = g * GRPB + bh * 16;
    const int arow = b0 + l15;   // A-operand (batch) row this lane loads
    const int jcol = j0 + l15;   // output hidden column

    float biasE[4], biasD[4];
    #pragma unroll
    for (int q = 0; q < 4; ++q) {
        biasE[q] = enc_b[q * HID + jcol];
        biasD[q] = dec_b[q * HID + jcol];
    }
    float cacc[4] = {0.f, 0.f, 0.f, 0.f};

    bf16x8 Breg[40];
    const int kc0 = gp * 320;    // K-half base for K=640 phases

    // ---- encoder weight fragments (K=640), pinned in VGPRs
    #pragma unroll
    for (int q = 0; q < 4; ++q)
        #pragma unroll
        for (int i = 0; i < 10; ++i)
            Breg[q * 10 + i] = *(const bf16x8*)(
                Wenc + (size_t)(q * HID + jcol) * 640 + kc0 + i * 32 + l4 * 8);
    #pragma unroll
    for (int n = 0; n < 40; ++n) asm volatile("" : "+v"(Breg[n]));

    // ================= encoder: t = 0..167 =================
    for (int t = 0; t < TIN; ++t) {
        if (t > 0) group_wait(flags, g, tid, (unsigned)t);
        const bf16_t* hb = (t & 1) ? hbufB : hbufA;
        bf16_t* hn       = (t & 1) ? hbufA : hbufB;
        f32x4 acc[4];
        #pragma unroll
        for (int q = 0; q < 4; ++q) {
            float bv = (gp == 0) ? biasE[q] : 0.f;
            acc[q] = (f32x4){bv, bv, bv, bv};
        }
        const bf16_t* xb  = Xbf + ((size_t)t * BATCH + arow) * FEAT + l4 * 8;
        const bf16_t* hbp = hb + (size_t)arow * HID + l4 * 8;
        #pragma unroll
        for (int i = 0; i < 10; ++i) {
            int kc = kc0 + i * 32;
            bf16x8 a;
            if (kc < FEAT) a = *(const bf16x8*)(xb + kc);
            else           a = ld_h8(hbp + (kc - FEAT));
            #pragma unroll
            for (int q = 0; q < 4; ++q)
                acc[q] = __builtin_amdgcn_mfma_f32_16x16x32_bf16(a, Breg[q * 10 + i], acc[q], 0, 0, 0);
        }
        cell_finish(acc, cacc, Ex, gp, bh, l4, l15, b0, jcol, hn);
        group_arrive(flags, g, jt, tid, (unsigned)(t + 1));
    }

    // ---- decoder step 0 weights (Wdec1, K=640) -- load before waiting
    #pragma unroll
    for (int q = 0; q < 4; ++q)
        #pragma unroll
        for (int i = 0; i < 10; ++i)
            Breg[q * 10 + i] = *(const bf16x8*)(
                Wdec1 + (size_t)(q * HID + jcol) * 640 + kc0 + i * 32 + l4 * 8);
    #pragma unroll
    for (int n = 0; n < 40; ++n) asm volatile("" : "+v"(Breg[n]));

    // ================= decoder step 0: t = 168 =================
    {
        const int t = TIN;
        group_wait(flags, g, tid, (unsigned)t);
        // h_168 lives in hbufA (written at t=167, TIN even)
        f32x4 acc[4];
        #pragma unroll
        for (int q = 0; q < 4; ++q) {
            float bv = (gp == 0) ? biasD[q] : 0.f;
            acc[q] = (f32x4){bv, bv, bv, bv};
        }
        const bf16_t* xb  = Xbf + ((size_t)(TIN - 1) * BATCH + arow) * FEAT + l4 * 8;
        const bf16_t* hbp = hbufA + (size_t)arow * HID + l4 * 8;
        #pragma unroll
        for (int i = 0; i < 10; ++i) {
            int kc = kc0 + i * 32;
            bf16x8 a;
            if (kc < FEAT) a = *(const bf16x8*)(xb + kc);
            else           a = ld_h8(hbp + (kc - FEAT));
            #pragma unroll
            for (int q = 0; q < 4; ++q)
                acc[q] = __builtin_amdgcn_mfma_f32_16x16x32_bf16(a, Breg[q * 10 + i], acc[q], 0, 0, 0);
        }
        cell_finish(acc, cacc, Ex, gp, bh, l4, l15, b0, jcol, Hdec);
        group_arrive(flags, g, jt, tid, (unsigned)(t + 1));
    }

    // ---- folded decoder weights (Wcomb, K=512)
    const int kd0 = gp * 256;
    #pragma unroll
    for (int q = 0; q < 4; ++q)
        #pragma unroll
        for (int i = 0; i < 8; ++i)
            Breg[q * 8 + i] = *(const bf16x8*)(
                Wcomb + (size_t)(q * HID + jcol) * HID + kd0 + i * 32 + l4 * 8);
    #pragma unroll
    for (int n = 0; n < 32; ++n) asm volatile("" : "+v"(Breg[n]));

    // ================= decoder: t = 169..215 =================
    for (int t = TIN + 1; t < NSTEPS; ++t) {
        group_wait(flags, g, tid, (unsigned)t);
        const bf16_t* hprev = Hdec + (size_t)(t - 1 - TIN) * BATCH * HID
                                   + (size_t)arow * HID + l4 * 8;
        f32x4 acc[4];
        #pragma unroll
        for (int q = 0; q < 4; ++q) {
            float bv = (gp == 0) ? biasD[q] : 0.f;
            acc[q] = (f32x4){bv, bv, bv, bv};
        }
        #pragma unroll
        for (int i = 0; i < 8; ++i) {
            bf16x8 a = ld_h8(hprev + kd0 + i * 32);
            #pragma unroll
            for (int q = 0; q < 4; ++q)
                acc[q] = __builtin_amdgcn_mfma_f32_16x16x32_bf16(a, Breg[q * 8 + i], acc[q], 0, 0, 0);
        }
        cell_finish(acc, cacc, Ex, gp, bh, l4, l15, b0, jcol,
                    Hdec + (size_t)(t - TIN) * BATCH * HID);
        group_arrive(flags, g, jt, tid, (unsigned)(t + 1));
    }
}

// ---------------------------------------------------------------------------
// Final projection: out[b,t,f] = sum_j Hdec[t][b][j] * Wlin[f][j]
__global__ __launch_bounds__(128)
void final_proj_kernel(const bf16_t* __restrict__ Hdec, const bf16_t* __restrict__ Wlin,
                       float* __restrict__ out) {
    int tid = threadIdx.x;
    int wv = tid >> 6, lane = tid & 63;
    int l15 = lane & 15, l4 = lane >> 4;
    int row0 = blockIdx.x * 32 + wv * 16;
    const bf16_t* arow = Hdec + (size_t)(row0 + l15) * HID;
    f32x4 acc[8];
    #pragma unroll
    for (int n = 0; n < 8; ++n) acc[n] = (f32x4){0.f, 0.f, 0.f, 0.f};
    #pragma unroll 4
    for (int kc = 0; kc < HID; kc += 32) {
        bf16x8 af = *(const bf16x8*)(arow + kc + l4 * 8);
        #pragma unroll
        for (int n = 0; n < 8; ++n) {
            bf16x8 bfr = *(const bf16x8*)(Wlin + (size_t)(n * 16 + l15) * HID + kc + l4 * 8);
            acc[n] = __builtin_amdgcn_mfma_f32_16x16x32_bf16(af, bfr, acc[n], 0, 0, 0);
        }
    }
    #pragma unroll
    for (int n = 0; n < 8; ++n) {
        int f = n * 16 + l15;
        #pragma unroll
        for (int r = 0; r < 4; ++r) {
            int row = row0 + l4 * 4 + r;
            int t = row >> 8;
            int b = row & 255;
            out[(size_t)b * (TOUT * FEAT) + (size_t)t * FEAT + f] = acc[n][r];
        }
    }
}

// ---------------------------------------------------------------------------
extern "C" void kernel_launch(void* const* d_in, const int* in_sizes, int n_in,
                              void* d_out, int out_size, void* d_ws, size_t ws_size,
                              hipStream_t stream) {
    const float* x       = (const float*)d_in[0];
    const float* enc_Wih = (const float*)d_in[1];
    const float* enc_Whh = (const float*)d_in[2];
    const float* enc_b   = (const float*)d_in[3];
    const float* dec_Wih = (const float*)d_in[4];
    const float* dec_Whh = (const float*)d_in[5];
    const float* dec_b   = (const float*)d_in[6];
    const float* W_lin   = (const float*)d_in[7];
    float* out = (float*)d_out;

    char* p = (char*)d_ws;
    auto alloc = [&](size_t bytes) -> void* {
        void* r = (void*)p;
        p += (bytes + 255) & ~(size_t)255;
        return r;
    };
    bf16_t* Xbf    = (bf16_t*)alloc((size_t)TIN * BATCH * FEAT * 2);   // 11 MB
    bf16_t* Wenc   = (bf16_t*)alloc((size_t)2048 * 640 * 2);           // 2.6 MB
    bf16_t* Wdec1  = (bf16_t*)alloc((size_t)2048 * 640 * 2);           // 2.6 MB
    bf16_t* Wcomb  = (bf16_t*)alloc((size_t)2048 * HID * 2);           // 2.1 MB
    bf16_t* Wlinb  = (bf16_t*)alloc((size_t)FEAT * HID * 2);           // 128 KB
    bf16_t* hbufA  = (bf16_t*)alloc((size_t)BATCH * HID * 2);          // 256 KB
    bf16_t* hbufB  = (bf16_t*)alloc((size_t)BATCH * HID * 2);          // 256 KB
    bf16_t* Hdec   = (bf16_t*)alloc((size_t)TOUT * BATCH * HID * 2);   // 12.6 MB
    unsigned int* flags = (unsigned int*)alloc((size_t)NGRP * NJT * 4);

    // per-launch state init (replay-safe)
    (void)hipMemsetAsync(hbufA, 0, (size_t)BATCH * HID * 2, stream);
    (void)hipMemsetAsync(flags, 0, (size_t)NGRP * NJT * 4, stream);

    // precompute
    cast_x_kernel<<<(BATCH * TIN * (FEAT / 4) + 255) / 256, 256, 0, stream>>>(x, Xbf);
    cast_wcat_kernel<<<(2048 * 160 + 255) / 256, 256, 0, stream>>>(enc_Wih, enc_Whh, Wenc);
    cast_wcat_kernel<<<(2048 * 160 + 255) / 256, 256, 0, stream>>>(dec_Wih, dec_Whh, Wdec1);
    cast_wlin_kernel<<<(FEAT * HID / 4 + 255) / 256, 256, 0, stream>>>(W_lin, Wlinb);
    build_wcomb_kernel<<<dim3(2048 / 64, HID / 64), 256, 0, stream>>>(dec_Wih, dec_Whh, W_lin, Wcomb);

    // all 216 recurrent steps in one persistent kernel
    lstm_persist<<<NGRP * NJT, 256, 0, stream>>>(Xbf, Wenc, enc_b, Wdec1, Wcomb, dec_b,
                                                 hbufA, hbufB, Hdec, flags);

    // batched output projection (48 x 256 rows @ W_lin^T)
    final_proj_kernel<<<(TOUT * BATCH) / 32, 128, 0, stream>>>(Hdec, Wlinb, out);
}